// Round 1
// baseline (26416.537 us; speedup 1.0000x reference)
//
#include <hip/hip_runtime.h>
#include <math.h>

#define Bsz 64
#define Tsz 1024
#define Isz 128
#define Hsz 512
#define KH  256   // H/2
#define Osz 10

// ---------------------------------------------------------------------------
// Simple register-tiled GEMM: C[M,N] = A[M,K] @ Bw[K,N] + bias[N]
// BM=BN=64, BK=32, 256 threads, 4x4 micro-tile. A staged in LDS; Bw streamed
// from global (small weight matrices, L2-resident, broadcast across blocks).
// Requires M%64==0, N%64==0, K%32==0 (holds for all uses here).
// ---------------------------------------------------------------------------
__global__ __launch_bounds__(256) void gemm_bias_kernel(
    const float* __restrict__ A, const float* __restrict__ Bw,
    const float* __restrict__ bias, float* __restrict__ C,
    int M, int N, int K)
{
  __shared__ float As[32][65];
  const int tid = threadIdx.x;
  const int m0 = blockIdx.x * 64;
  const int n0 = blockIdx.y * 64;
  const int ty = tid >> 4, tx = tid & 15;

  float acc[4][4] = {{0.f}};

  for (int kk = 0; kk < K; kk += 32) {
    __syncthreads();
#pragma unroll
    for (int i = tid; i < 64 * 32; i += 256) {
      int m = i >> 5, k = i & 31;
      As[k][m] = A[(size_t)(m0 + m) * K + kk + k];
    }
    __syncthreads();
#pragma unroll
    for (int k = 0; k < 32; ++k) {
      float a0 = As[k][ty * 4 + 0];
      float a1 = As[k][ty * 4 + 1];
      float a2 = As[k][ty * 4 + 2];
      float a3 = As[k][ty * 4 + 3];
      const float4 bv = *(const float4*)(&Bw[(size_t)(kk + k) * N + n0 + tx * 4]);
      acc[0][0] += a0 * bv.x; acc[0][1] += a0 * bv.y; acc[0][2] += a0 * bv.z; acc[0][3] += a0 * bv.w;
      acc[1][0] += a1 * bv.x; acc[1][1] += a1 * bv.y; acc[1][2] += a1 * bv.z; acc[1][3] += a1 * bv.w;
      acc[2][0] += a2 * bv.x; acc[2][1] += a2 * bv.y; acc[2][2] += a2 * bv.z; acc[2][3] += a2 * bv.w;
      acc[3][0] += a3 * bv.x; acc[3][1] += a3 * bv.y; acc[3][2] += a3 * bv.z; acc[3][3] += a3 * bv.w;
    }
  }

  const float4 bb = *(const float4*)(&bias[n0 + tx * 4]);
#pragma unroll
  for (int i = 0; i < 4; ++i) {
    float4 v;
    v.x = acc[i][0] + bb.x; v.y = acc[i][1] + bb.y;
    v.z = acc[i][2] + bb.z; v.w = acc[i][3] + bb.w;
    *(float4*)(&C[(size_t)(m0 + ty * 4 + i) * N + n0 + tx * 4]) = v;
  }
}

// ---------------------------------------------------------------------------
// Transpose W_rec (512x512) -> WrecT so scan's drive loop is lane-coalesced:
// WrecT[i*512 + j] = W_rec[j*512 + i]
// ---------------------------------------------------------------------------
__global__ __launch_bounds__(256) void transpose512_kernel(
    const float* __restrict__ in, float* __restrict__ out)
{
  __shared__ float tile[32][33];
  const int bx = blockIdx.x & 15, by = blockIdx.x >> 4;
  const int tx = threadIdx.x & 31, ty4 = (threadIdx.x >> 5) * 4;
#pragma unroll
  for (int j = 0; j < 4; ++j)
    tile[ty4 + j][tx] = in[(size_t)(by * 32 + ty4 + j) * 512 + bx * 32 + tx];
  __syncthreads();
#pragma unroll
  for (int j = 0; j < 4; ++j)
    out[(size_t)(bx * 32 + ty4 + j) * 512 + by * 32 + tx] = tile[tx][ty4 + j];
}

// ---------------------------------------------------------------------------
// The sequential scan. One workgroup per batch element (batch rows are fully
// independent), h lives in LDS, weights streamed from L2 each step.
// Fuses the output projection (O=10), so hs is never materialized.
//   A[k]    = relu(U[b,t,k] + sum_j h[j]*W_tau1[512+j, k])       (b_tau1 in U)
//   tau[j]  = 5 + 45*sigmoid(sum_k A[k]*W_tau2[k,j] + b_tau2[j])
//   drive[j]= tanh(xp[b,t,j] + sum_i h[i]*WrecT[i,j] + bias[j])
//   h'[j]   = h[j] + (drive[j]-h[j])/tau[j]
//   out[b,t,o] = sum_j h'[j]*W_out[j,o] + b_out[o]
// ---------------------------------------------------------------------------
__global__ __launch_bounds__(512) void scan_kernel(
    const float* __restrict__ xp,      // [B,T,H]
    const float* __restrict__ U,       // [B,T,KH]  (b_tau1 already added)
    const float* __restrict__ W_tau1,  // [2H, KH]
    const float* __restrict__ W_tau2,  // [KH, H]
    const float* __restrict__ b_tau2,  // [H]
    const float* __restrict__ WrecT,   // [H,H] transposed
    const float* __restrict__ bias,    // [H]
    const float* __restrict__ W_out,   // [H, O]
    const float* __restrict__ b_out,   // [O]
    float* __restrict__ out)           // [B,T,O]
{
  const int b = blockIdx.x;
  const int tid = threadIdx.x;

  __shared__ float h[Hsz];
  __shared__ float Abuf[KH];
  __shared__ float part[2][KH];
  __shared__ float red[16][Osz];

  const float* __restrict__ W1b = W_tau1 + (size_t)Hsz * KH;  // rows 512..1023

  h[tid] = 0.f;
  __syncthreads();

  const int k = tid & 255;
  const int halfsel = tid >> 8;  // 0 or 1
  const int j0 = halfsel * 256;

  for (int t = 0; t < Tsz; ++t) {
    // --- tau-MLP layer 1 (h part), split-K by 2 across the 512 threads ---
    {
      float p = 0.f;
      const float* __restrict__ w = W1b + (size_t)j0 * KH + k;
#pragma unroll 8
      for (int j = 0; j < 256; ++j)
        p += h[j0 + j] * w[(size_t)j * KH];
      part[halfsel][k] = p;
    }
    __syncthreads();
    if (tid < KH) {
      float a = U[((size_t)b * Tsz + t) * KH + tid] + part[0][tid] + part[1][tid];
      Abuf[tid] = fmaxf(a, 0.f);
    }
    __syncthreads();

    // --- tau (layer 2 + sigmoid), one column per thread ---
    float s = 0.f;
#pragma unroll 8
    for (int kk = 0; kk < KH; ++kk)
      s += Abuf[kk] * W_tau2[(size_t)kk * Hsz + tid];
    s += b_tau2[tid];
    const float tau = 5.0f + 45.0f / (1.0f + expf(-s));

    // --- drive = tanh(xp + h @ W_rec^T + bias), one column per thread ---
    float d = 0.f;
#pragma unroll 8
    for (int i = 0; i < Hsz; ++i)
      d += h[i] * WrecT[(size_t)i * Hsz + tid];
    d += xp[((size_t)b * Tsz + t) * Hsz + tid] + bias[tid];
    const float drive = tanhf(d);

    const float hold = h[tid];
    const float hnew = hold + (drive - hold) / tau;

    __syncthreads();   // all reads of old h complete
    h[tid] = hnew;
    __syncthreads();

    // --- fused output projection: out[b,t,:] = h' @ W_out + b_out ---
    if (tid < 160) {
      const int o = tid >> 4, seg = tid & 15;
      float acc = 0.f;
#pragma unroll
      for (int j = seg * 32; j < seg * 32 + 32; ++j)
        acc += h[j] * W_out[(size_t)j * Osz + o];
      red[seg][o] = acc;
    }
    __syncthreads();
    if (tid < Osz) {
      float acc = b_out[tid];
#pragma unroll
      for (int sg = 0; sg < 16; ++sg) acc += red[sg][tid];
      out[((size_t)b * Tsz + t) * Osz + tid] = acc;
    }
    // next iteration's first __syncthreads orders these reads vs. new writes
  }
}

// ---------------------------------------------------------------------------
extern "C" void kernel_launch(void* const* d_in, const int* in_sizes, int n_in,
                              void* d_out, int out_size, void* d_ws, size_t ws_size,
                              hipStream_t stream) {
  (void)in_sizes; (void)n_in; (void)out_size; (void)ws_size;

  const float* x      = (const float*)d_in[0];   // [B,T,I]
  const float* W_in   = (const float*)d_in[1];   // [I,H]
  const float* b_in   = (const float*)d_in[2];   // [H]
  const float* W_rec  = (const float*)d_in[3];   // [H,H]
  const float* bias   = (const float*)d_in[4];   // [H]
  const float* W_tau1 = (const float*)d_in[5];   // [2H, KH]
  const float* b_tau1 = (const float*)d_in[6];   // [KH]
  const float* W_tau2 = (const float*)d_in[7];   // [KH, H]
  const float* b_tau2 = (const float*)d_in[8];   // [H]
  const float* W_out  = (const float*)d_in[9];   // [H,O]
  const float* b_out  = (const float*)d_in[10];  // [O]
  float* out = (float*)d_out;

  // workspace layout
  char* ws = (char*)d_ws;
  float* xp    = (float*)ws;                                  // 64*1024*512*4 = 128 MiB
  float* U     = (float*)(ws + (size_t)Bsz * Tsz * Hsz * 4);  // 64*1024*256*4 =  64 MiB
  float* WrecT = (float*)(ws + (size_t)Bsz * Tsz * Hsz * 4
                             + (size_t)Bsz * Tsz * KH * 4);   // 1 MiB

  const int M = Bsz * Tsz;  // 65536

  // 1) xp = x @ W_in + b_in            [65536,128] @ [128,512]
  {
    dim3 grid(M / 64, Hsz / 64);
    gemm_bias_kernel<<<grid, 256, 0, stream>>>(x, W_in, b_in, xp, M, Hsz, Isz);
  }
  // 2) WrecT = W_rec^T (independent of 1)
  transpose512_kernel<<<256, 256, 0, stream>>>(W_rec, WrecT);
  // 3) U = xp @ W_tau1[:512] + b_tau1   [65536,512] @ [512,256]
  {
    dim3 grid(M / 64, KH / 64);
    gemm_bias_kernel<<<grid, 256, 0, stream>>>(xp, W_tau1, b_tau1, U, M, KH, Hsz);
  }
  // 4) sequential scan + fused output projection
  scan_kernel<<<Bsz, 512, 0, stream>>>(xp, U, W_tau1, W_tau2, b_tau2,
                                       WrecT, bias, W_out, b_out, out);
}

// Round 2
// 13516.936 us; speedup vs baseline: 1.9543x; 1.9543x over previous
//
#include <hip/hip_runtime.h>
#include <math.h>

#define Bsz 64
#define Tsz 1024
#define Isz 128
#define Hsz 512
#define KH  256   // H/2
#define Osz 10

// ---------------------------------------------------------------------------
// Register-tiled fp32 GEMM: C[M,N] = A[M,K] @ Bw[K,N] + bias[N]
// Used for the two precomputable projections (xp, U).
// ---------------------------------------------------------------------------
__global__ __launch_bounds__(256) void gemm_bias_kernel(
    const float* __restrict__ A, const float* __restrict__ Bw,
    const float* __restrict__ bias, float* __restrict__ C,
    int M, int N, int K)
{
  __shared__ float As[32][65];
  const int tid = threadIdx.x;
  const int m0 = blockIdx.x * 64;
  const int n0 = blockIdx.y * 64;
  const int ty = tid >> 4, tx = tid & 15;

  float acc[4][4] = {{0.f}};

  for (int kk = 0; kk < K; kk += 32) {
    __syncthreads();
#pragma unroll
    for (int i = tid; i < 64 * 32; i += 256) {
      int m = i >> 5, k = i & 31;
      As[k][m] = A[(size_t)(m0 + m) * K + kk + k];
    }
    __syncthreads();
#pragma unroll
    for (int k = 0; k < 32; ++k) {
      float a0 = As[k][ty * 4 + 0];
      float a1 = As[k][ty * 4 + 1];
      float a2 = As[k][ty * 4 + 2];
      float a3 = As[k][ty * 4 + 3];
      const float4 bv = *(const float4*)(&Bw[(size_t)(kk + k) * N + n0 + tx * 4]);
      acc[0][0] += a0 * bv.x; acc[0][1] += a0 * bv.y; acc[0][2] += a0 * bv.z; acc[0][3] += a0 * bv.w;
      acc[1][0] += a1 * bv.x; acc[1][1] += a1 * bv.y; acc[1][2] += a1 * bv.z; acc[1][3] += a1 * bv.w;
      acc[2][0] += a2 * bv.x; acc[2][1] += a2 * bv.y; acc[2][2] += a2 * bv.z; acc[2][3] += a2 * bv.w;
      acc[3][0] += a3 * bv.x; acc[3][1] += a3 * bv.y; acc[3][2] += a3 * bv.z; acc[3][3] += a3 * bv.w;
    }
  }

  const float4 bb = *(const float4*)(&bias[n0 + tx * 4]);
#pragma unroll
  for (int i = 0; i < 4; ++i) {
    float4 v;
    v.x = acc[i][0] + bb.x; v.y = acc[i][1] + bb.y;
    v.z = acc[i][2] + bb.z; v.w = acc[i][3] + bb.w;
    *(float4*)(&C[(size_t)(m0 + ty * 4 + i) * N + n0 + tx * 4]) = v;
  }
}

// ---------------------------------------------------------------------------
// bf16 (RNE) pack helpers. Weights are finite; no NaN handling needed.
// low 16 bits  = element of even row (pairs with h2.x)
// high 16 bits = element of odd  row (pairs with h2.y)
// unpack: lo = u<<16, hi = u & 0xffff0000
// ---------------------------------------------------------------------------
__device__ __forceinline__ unsigned bf16rne(float f) {
  unsigned u = __float_as_uint(f);
  return (u + 0x7fffu + ((u >> 16) & 1u)) >> 16;
}

// Generic: in [R][C] f32 -> out [R/2][C] u32, pairing consecutive rows.
__global__ __launch_bounds__(256) void pack_rows_kernel(
    const float* __restrict__ in, unsigned* __restrict__ out, int R2, int C)
{
  int i = blockIdx.x * 256 + threadIdx.x;
  if (i >= R2 * C) return;
  int r2 = i / C, c = i - r2 * C;
  unsigned lo = bf16rne(in[(size_t)(2 * r2) * C + c]);
  unsigned hi = bf16rne(in[(size_t)(2 * r2 + 1) * C + c]);
  out[i] = lo | (hi << 16);
}

// W_rec [512][512] row-major -> P0[i2][j] = pack(W_rec[j][2*i2], W_rec[j][2*i2+1])
// (transposed so scan's drive loop is lane-coalesced over j)
__global__ __launch_bounds__(256) void pack_wrecT_kernel(
    const float* __restrict__ W_rec, unsigned* __restrict__ P0)
{
  int i = blockIdx.x * 256 + threadIdx.x;   // i = i2*512 + j, i2 in [0,256)
  if (i >= 256 * Hsz) return;
  int i2 = i >> 9, j = i & 511;
  unsigned lo = bf16rne(W_rec[(size_t)j * Hsz + 2 * i2]);
  unsigned hi = bf16rne(W_rec[(size_t)j * Hsz + 2 * i2 + 1]);
  P0[i] = lo | (hi << 16);
}

// ---------------------------------------------------------------------------
// Sequential scan. One WG per batch element. bf16x2-packed weights (L2-hot),
// fp32 state. 3 barriers/step via LDS double-buffered h. h_t overwrites the
// dead xp[b,t,:] slot (xps doubles as the hs buffer for the epilogue GEMM).
// ---------------------------------------------------------------------------
__global__ __launch_bounds__(512) void scan_kernel(
    float* __restrict__ xps,           // in: xp [B,T,H]; out: hs [B,T,H]
    const float* __restrict__ U,       // [B,T,KH] (b_tau1 already added)
    const unsigned* __restrict__ P0,   // [256][512] packed W_rec^T pairs
    const unsigned* __restrict__ P1,   // [256][256] packed W_tau1[512:] row-pairs
    const unsigned* __restrict__ P2,   // [128][512] packed W_tau2 row-pairs
    const float* __restrict__ bias,    // [H]
    const float* __restrict__ b_tau2)  // [H]
{
  const int b = blockIdx.x;
  const int tid = threadIdx.x;

  __shared__ float hbuf[2][Hsz];
  __shared__ float Abuf[KH];
  __shared__ float part[2][KH];

  const float bias_r = bias[tid];
  const float bt2_r  = b_tau2[tid];
  const int k = tid & 255;
  const int halfsel = tid >> 8;   // 0 or 1

  hbuf[0][tid] = 0.f;

  float* xprow = xps + (size_t)b * Tsz * Hsz;
  const float* Urow = U + (size_t)b * Tsz * KH;
  const unsigned* P0c = P0 + tid;            // column tid
  const unsigned* P2c = P2 + tid;
  const unsigned* P1c = P1 + (size_t)(halfsel * 128) * KH + k;
  const float* hpbase_off;  (void)hpbase_off;

  __syncthreads();

  for (int t = 0; t < Tsz; ++t) {
    const float* hc = hbuf[t & 1];
    float* hn = hbuf[(t + 1) & 1];

    const float xpv = xprow[tid];                 // prefetch, used late
    float Uv = 0.f;
    if (tid < KH) Uv = Urow[tid];                 // prefetch, used after sync1

    // --- drive partial: d = sum_i h[i] * W_rec[tid][i]  (bf16x2 pairs) ---
    float d = 0.f;
#pragma unroll 16
    for (int i2 = 0; i2 < 256; ++i2) {
      unsigned w = P0c[(size_t)i2 * Hsz];
      float2 h2 = *(const float2*)&hc[2 * i2];
      d = fmaf(h2.x, __uint_as_float(w << 16), d);
      d = fmaf(h2.y, __uint_as_float(w & 0xffff0000u), d);
    }

    // --- tau-MLP layer 1 (h part), split-K by 2 ---
    {
      float p = 0.f;
      const float* hp = &hc[halfsel * 256];
#pragma unroll 16
      for (int j2 = 0; j2 < 128; ++j2) {
        unsigned w = P1c[(size_t)j2 * KH];
        float2 h2 = *(const float2*)&hp[2 * j2];
        p = fmaf(h2.x, __uint_as_float(w << 16), p);
        p = fmaf(h2.y, __uint_as_float(w & 0xffff0000u), p);
      }
      part[halfsel][k] = p;
    }
    __syncthreads();                              // sync1

    if (tid < KH)
      Abuf[tid] = fmaxf(Uv + part[0][tid] + part[1][tid], 0.f);
    __syncthreads();                              // sync2

    // --- tau layer 2 + sigmoid ---
    float s = bt2_r;
#pragma unroll 16
    for (int k2 = 0; k2 < 128; ++k2) {
      unsigned w = P2c[(size_t)k2 * Hsz];
      float2 a2 = *(const float2*)&Abuf[2 * k2];
      s = fmaf(a2.x, __uint_as_float(w << 16), s);
      s = fmaf(a2.y, __uint_as_float(w & 0xffff0000u), s);
    }
    const float tau = 5.0f + 45.0f / (1.0f + __expf(-s));

    const float drive = tanhf(d + xpv + bias_r);
    const float hold = hc[tid];
    const float hnew = hold + (drive - hold) / tau;

    hn[tid] = hnew;
    xprow[tid] = hnew;                            // hs[b][t][:] = h_t (slot is dead)
    __syncthreads();                              // sync3

    xprow += Hsz;
    Urow  += KH;
  }
}

// ---------------------------------------------------------------------------
// Epilogue: out[m,o] = hs[m,:] @ W_out[:,o] + b_out[o], m in [0,65536), O=10.
// Block = 16 rows x 16 lanes (o<10 active).
// ---------------------------------------------------------------------------
__global__ __launch_bounds__(256) void outproj_kernel(
    const float* __restrict__ hs, const float* __restrict__ W_out,
    const float* __restrict__ b_out, float* __restrict__ out)
{
  const int m = blockIdx.x * 16 + (threadIdx.x >> 4);
  const int o = threadIdx.x & 15;
  if (o >= Osz) return;
  const float* hrow = hs + (size_t)m * Hsz;
  float acc = b_out[o];
#pragma unroll 8
  for (int kk = 0; kk < Hsz; ++kk)
    acc = fmaf(hrow[kk], W_out[(size_t)kk * Osz + o], acc);
  out[(size_t)m * Osz + o] = acc;
}

// ---------------------------------------------------------------------------
extern "C" void kernel_launch(void* const* d_in, const int* in_sizes, int n_in,
                              void* d_out, int out_size, void* d_ws, size_t ws_size,
                              hipStream_t stream) {
  (void)in_sizes; (void)n_in; (void)out_size; (void)ws_size;

  const float* x      = (const float*)d_in[0];   // [B,T,I]
  const float* W_in   = (const float*)d_in[1];   // [I,H]
  const float* b_in   = (const float*)d_in[2];   // [H]
  const float* W_rec  = (const float*)d_in[3];   // [H,H]
  const float* bias   = (const float*)d_in[4];   // [H]
  const float* W_tau1 = (const float*)d_in[5];   // [2H, KH]
  const float* b_tau1 = (const float*)d_in[6];   // [KH]
  const float* W_tau2 = (const float*)d_in[7];   // [KH, H]
  const float* b_tau2 = (const float*)d_in[8];   // [H]
  const float* W_out  = (const float*)d_in[9];   // [H,O]
  const float* b_out  = (const float*)d_in[10];  // [O]
  float* out = (float*)d_out;

  // workspace layout
  char* ws = (char*)d_ws;
  size_t off = 0;
  float* xps = (float*)(ws + off); off += (size_t)Bsz * Tsz * Hsz * 4;  // 128 MiB (xp, then hs in-place)
  float* U   = (float*)(ws + off); off += (size_t)Bsz * Tsz * KH * 4;   //  64 MiB
  unsigned* P0 = (unsigned*)(ws + off); off += (size_t)256 * Hsz * 4;   // 512 KiB
  unsigned* P1 = (unsigned*)(ws + off); off += (size_t)256 * KH  * 4;   // 256 KiB
  unsigned* P2 = (unsigned*)(ws + off); off += (size_t)128 * Hsz * 4;   // 256 KiB

  const int M = Bsz * Tsz;  // 65536

  // 1) weight repack (independent of the GEMMs)
  pack_wrecT_kernel<<<(256 * Hsz + 255) / 256, 256, 0, stream>>>(W_rec, P0);
  pack_rows_kernel<<<(256 * KH + 255) / 256, 256, 0, stream>>>(
      W_tau1 + (size_t)Hsz * KH, P1, 256, KH);
  pack_rows_kernel<<<(128 * Hsz + 255) / 256, 256, 0, stream>>>(W_tau2, P2, 128, Hsz);

  // 2) xp = x @ W_in + b_in            [65536,128] @ [128,512]
  {
    dim3 grid(M / 64, Hsz / 64);
    gemm_bias_kernel<<<grid, 256, 0, stream>>>(x, W_in, b_in, xps, M, Hsz, Isz);
  }
  // 3) U = xp @ W_tau1[:512] + b_tau1   [65536,512] @ [512,256]
  {
    dim3 grid(M / 64, KH / 64);
    gemm_bias_kernel<<<grid, 256, 0, stream>>>(xps, W_tau1, b_tau1, U, M, KH, Hsz);
  }
  // 4) sequential scan (writes h_t over xp slots)
  scan_kernel<<<Bsz, 512, 0, stream>>>(xps, U, P0, P1, P2, bias, b_tau2);
  // 5) epilogue output projection
  outproj_kernel<<<M / 16, 256, 0, stream>>>(xps, W_out, b_out, out);
}